// Round 1
// 460.062 us; speedup vs baseline: 1.0672x; 1.0672x over previous
//
#include <hip/hip_runtime.h>
#include <hip/hip_fp16.h>
#include <stdint.h>

// InstantNGP hash-grid embedding, round 4.
// Round-3 counters: gather_lvl 309us, HBM 728 GB/s (9%), VALUBusy 13.6%,
// occupancy 88% -> request-throughput bound (~0.67 lane-addr/cy/CU at the
// L1/TA tag pipe). Attack: levels 0..7 restaged CELL-MAJOR (8 corner half2
// contiguous per cell, 32B aligned) -> 2x dwordx4 to ONE 64B line per point
// instead of 8 divergent dwords. Per-point lane-requests: 128 -> 80.
// Hash levels (8..15) irreducible: XOR-hash scatters corners (x-pairs are
// already same-line 15/16 of the time since PRIME_x==1).

#define N_LEVELS   16
#define LOG2_T     19
#define TABLE_SIZE (1u << LOG2_T)
#define HASH_MASK  (TABLE_SIZE - 1u)
#define P1 2654435761u
#define P2 805459861u
#define N_DENSE    8          // levels 0..7 use dense restaging

__constant__ int   c_res[N_LEVELS]   = {16, 20, 25, 32, 40, 50, 64, 80,
                                        101, 128, 161, 203, 256, 322, 406, 512};
// scale = res/2 (exact fp32); rel=(x+1)*scale matches ref to <=1 ulp.
__constant__ float c_scale[N_LEVELS] = {8.0f, 10.0f, 12.5f, 16.0f, 20.0f, 25.0f,
                                        32.0f, 40.0f, 50.5f, 64.0f, 80.5f, 101.5f,
                                        128.0f, 161.0f, 203.0f, 256.0f};

// ---- vertex-dense layout (fallback tier): dims S=R+1, offsets in half2 ----
__constant__ uint32_t c_dim[N_DENSE]  = {17, 21, 26, 33, 41, 51, 65, 81};
__constant__ uint32_t c_doff[N_DENSE] = {0, 4913, 14174, 31750,
                                         67687, 136608, 269259, 543884};
#define DENSE_TOTAL 1075325u

// ---- cell-major layout (preferred tier): R^3 cells, 32B (8 half2) each ----
// offsets in CELLS: prefix sums of {16^3,20^3,25^3,32^3,40^3,50^3,64^3,80^3}
__constant__ uint32_t c_coff[N_DENSE] = {0, 4096, 12096, 27721,
                                         60489, 124489, 249489, 511633};
#define CELL_TOTAL 1023633u   // * 32B = 32.76 MB

// ---------------- pass 0a: fp16-convert hash tables (levels 8..15) ---------
__global__ __launch_bounds__(256) void conv_hash(
    const float2* __restrict__ emb, uint32_t* __restrict__ ht, int total)
{
    int i = blockIdx.x * 256 + threadIdx.x;
    if (i >= total) return;
    float2 v = emb[(size_t)N_DENSE * TABLE_SIZE + i];   // levels 8..15 contiguous
    __half2 h = __float22half2_rn(v);
    ht[i] = *(uint32_t*)&h;
}

// ---------------- pass 0b (preferred): build cell-major fp16 grids ---------
__global__ __launch_bounds__(256) void conv_cell(
    const float2* __restrict__ emb, uint4* __restrict__ cg)
{
    int l = blockIdx.y;
    uint32_t c = blockIdx.x * 256 + threadIdx.x;
    uint32_t R = (uint32_t)c_res[l];
    if (c >= R * R * R) return;
    uint32_t ix = c % R;
    uint32_t r  = c / R;
    uint32_t iy = r % R;
    uint32_t iz = r / R;

    const float2* __restrict__ tb = emb + (size_t)l * TABLE_SIZE;
    uint32_t a0 = ix,      a1 = ix + 1u;     // prime[0]==1
    uint32_t b0 = iy * P1, b1 = b0 + P1;
    uint32_t d0 = iz * P2, d1 = d0 + P2;

    float2 f0 = tb[(a0 ^ b0 ^ d0) & HASH_MASK];
    float2 f1 = tb[(a1 ^ b0 ^ d0) & HASH_MASK];
    float2 f2 = tb[(a0 ^ b1 ^ d0) & HASH_MASK];
    float2 f3 = tb[(a1 ^ b1 ^ d0) & HASH_MASK];
    float2 f4 = tb[(a0 ^ b0 ^ d1) & HASH_MASK];
    float2 f5 = tb[(a1 ^ b0 ^ d1) & HASH_MASK];
    float2 f6 = tb[(a0 ^ b1 ^ d1) & HASH_MASK];
    float2 f7 = tb[(a1 ^ b1 ^ d1) & HASH_MASK];

    __half2 h0 = __float22half2_rn(f0), h1 = __float22half2_rn(f1);
    __half2 h2 = __float22half2_rn(f2), h3 = __float22half2_rn(f3);
    __half2 h4 = __float22half2_rn(f4), h5 = __float22half2_rn(f5);
    __half2 h6 = __float22half2_rn(f6), h7 = __float22half2_rn(f7);

    uint32_t base = 2u * (c_coff[l] + c);
    cg[base]      = make_uint4(*(uint32_t*)&h0, *(uint32_t*)&h1,
                               *(uint32_t*)&h2, *(uint32_t*)&h3);
    cg[base + 1u] = make_uint4(*(uint32_t*)&h4, *(uint32_t*)&h5,
                               *(uint32_t*)&h6, *(uint32_t*)&h7);
}

// ---------------- pass 0b (fallback): vertex-dense fp16 grids --------------
__global__ __launch_bounds__(256) void conv_dense(
    const float2* __restrict__ emb, uint32_t* __restrict__ dn)
{
    int l = blockIdx.y;
    uint32_t v = blockIdx.x * 256 + threadIdx.x;
    uint32_t S = c_dim[l];
    if (v >= S * S * S) return;
    uint32_t ix = v % S;
    uint32_t r  = v / S;
    uint32_t iy = r % S;
    uint32_t iz = r / S;
    uint32_t h  = (ix ^ (iy * P1) ^ (iz * P2)) & HASH_MASK;
    float2 val  = emb[(size_t)l * TABLE_SIZE + h];
    __half2 hv  = __float22half2_rn(val);
    dn[c_doff[l] + v] = *(uint32_t*)&hv;
}

// ---------------- gather core ----------------------------------------------
template <bool CELL>
__device__ __forceinline__ void do_point(
    int l, int b, int npts,
    const float* __restrict__ x,
    const uint32_t* __restrict__ ht,
    const uint32_t* __restrict__ dn,
    const uint4*    __restrict__ cg,
    uint32_t* __restrict__ tmp)
{
    if (b >= npts) return;
    size_t xb = (size_t)b * 3;
    float xx = x[xb], xy = x[xb + 1], xz = x[xb + 2];

    float scale = c_scale[l];
    float hiv   = (float)c_res[l] - 1.0f;

    float rx = (xx + 1.0f) * scale;
    float ry = (xy + 1.0f) * scale;
    float rz = (xz + 1.0f) * scale;

    float fx = fminf(fmaxf(floorf(rx), 0.0f), hiv);
    float fy = fminf(fmaxf(floorf(ry), 0.0f), hiv);
    float fz = fminf(fmaxf(floorf(rz), 0.0f), hiv);

    float wx = rx - fx, wy = ry - fy, wz = rz - fz;
    uint32_t ix = (uint32_t)fx, iy = (uint32_t)fy, iz = (uint32_t)fz;

    uint32_t u0, u1, u2, u3, u4, u5, u6, u7;
    if (l < N_DENSE) {
        if constexpr (CELL) {                 // 2x dwordx4, same 64B line
            uint32_t R    = (uint32_t)c_res[l];
            uint32_t cidx = (iz * R + iy) * R + ix;
            uint32_t base = 2u * (c_coff[l] + cidx);
            uint4 lo = cg[base];
            uint4 hi = cg[base + 1u];
            u0 = lo.x; u1 = lo.y; u2 = lo.z; u3 = lo.w;
            u4 = hi.x; u5 = hi.y; u6 = hi.z; u7 = hi.w;
        } else {                              // vertex-dense: 8 dwords
            uint32_t S    = c_dim[l];
            uint32_t base = c_doff[l] + (iz * S + iy) * S + ix;
            uint32_t S2   = S * S;
            u0 = dn[base];           u1 = dn[base + 1];
            u2 = dn[base + S];       u3 = dn[base + S + 1];
            u4 = dn[base + S2];      u5 = dn[base + S2 + 1];
            u6 = dn[base + S2 + S];  u7 = dn[base + S2 + S + 1];
        }
    } else {                                  // hash path (fp16 table, 2MB)
        const uint32_t* __restrict__ tb = ht + (size_t)(l - N_DENSE) * TABLE_SIZE;
        uint32_t a0 = ix,      a1 = ix + 1u;  // prime[0]==1
        uint32_t b0 = iy * P1, b1 = b0 + P1;
        uint32_t c0 = iz * P2, c1 = c0 + P2;
        u0 = tb[(a0 ^ b0 ^ c0) & HASH_MASK];
        u1 = tb[(a1 ^ b0 ^ c0) & HASH_MASK];
        u2 = tb[(a0 ^ b1 ^ c0) & HASH_MASK];
        u3 = tb[(a1 ^ b1 ^ c0) & HASH_MASK];
        u4 = tb[(a0 ^ b0 ^ c1) & HASH_MASK];
        u5 = tb[(a1 ^ b0 ^ c1) & HASH_MASK];
        u6 = tb[(a0 ^ b1 ^ c1) & HASH_MASK];
        u7 = tb[(a1 ^ b1 ^ c1) & HASH_MASK];
    }

    float2 v0 = __half22float2(*(__half2*)&u0);
    float2 v1 = __half22float2(*(__half2*)&u1);
    float2 v2 = __half22float2(*(__half2*)&u2);
    float2 v3 = __half22float2(*(__half2*)&u3);
    float2 v4 = __half22float2(*(__half2*)&u4);
    float2 v5 = __half22float2(*(__half2*)&u5);
    float2 v6 = __half22float2(*(__half2*)&u6);
    float2 v7 = __half22float2(*(__half2*)&u7);

    float ux = 1.0f - wx, uy = 1.0f - wy, uz = 1.0f - wz;
    float w0 = ux * uy * uz, w1 = wx * uy * uz;
    float w2 = ux * wy * uz, w3 = wx * wy * uz;
    float w4 = ux * uy * wz, w5 = wx * uy * wz;
    float w6 = ux * wy * wz, w7 = wx * wy * wz;

    float o0 = w0 * v0.x + w1 * v1.x + w2 * v2.x + w3 * v3.x
             + w4 * v4.x + w5 * v5.x + w6 * v6.x + w7 * v7.x;
    float o1 = w0 * v0.y + w1 * v1.y + w2 * v2.y + w3 * v3.y
             + w4 * v4.y + w5 * v5.y + w6 * v6.y + w7 * v7.y;

    __half2 r = __float22half2_rn(make_float2(o0, o1));
    tmp[(size_t)l * npts + b] = *(uint32_t*)&r;
}

// grid.y = level (dispatch x-fastest -> level phases); 2 points/thread.
template <bool CELL>
__global__ __launch_bounds__(256) void gather_lvl(
    const float* __restrict__ x,
    const uint32_t* __restrict__ ht,
    const uint32_t* __restrict__ dn,
    const uint4*    __restrict__ cg,
    uint32_t* __restrict__ tmp, int npts)
{
    const int l  = blockIdx.y;
    const int bA = blockIdx.x * 512 + threadIdx.x;
    do_point<CELL>(l, bA,       npts, x, ht, dn, cg, tmp);
    do_point<CELL>(l, bA + 256, npts, x, ht, dn, cg, tmp);
}

// ---------------- pass 2: tmp[l][b] (half2) -> out[b][l] (float2) ----------
__global__ __launch_bounds__(256) void transpose_k(
    const uint32_t* __restrict__ tmp, float4* __restrict__ out4, int npts)
{
    __shared__ uint32_t sm[N_LEVELS][514];    // pad 2 -> <=2-way bank conflicts

    const int b0 = blockIdx.x * 512;
    const int t  = threadIdx.x;

    if (b0 + 512 <= npts) {
        #pragma unroll
        for (int l = 0; l < N_LEVELS; ++l) {
            uint2 u = *(const uint2*)&tmp[(size_t)l * npts + b0 + 2 * t];
            *(uint2*)&sm[l][2 * t] = u;       // single ds_write_b64
        }
        __syncthreads();
        #pragma unroll
        for (int k = 0; k < 16; ++k) {
            int q = k * 256 + t;              // float4 index in tile (0..4095)
            int p = q >> 3;                   // point in tile
            int j = q & 7;                    // float4 within point
            uint32_t a = sm[2 * j][p], b = sm[2 * j + 1][p];
            float2 f0 = __half22float2(*(__half2*)&a);
            float2 f1 = __half22float2(*(__half2*)&b);
            out4[(size_t)(b0 + p) * 8 + j] = make_float4(f0.x, f0.y, f1.x, f1.y);
        }
    } else {                                  // guarded tail tile
        for (int l = 0; l < N_LEVELS; ++l) {
            for (int s = 0; s < 2; ++s) {
                int b = b0 + 2 * t + s;
                if (b < npts) sm[l][2 * t + s] = tmp[(size_t)l * npts + b];
            }
        }
        __syncthreads();
        for (int k = 0; k < 16; ++k) {
            int q = k * 256 + t;
            int p = q >> 3, j = q & 7;
            if (b0 + p < npts) {
                uint32_t a = sm[2 * j][p], b = sm[2 * j + 1][p];
                float2 f0 = __half22float2(*(__half2*)&a);
                float2 f1 = __half22float2(*(__half2*)&b);
                out4[(size_t)(b0 + p) * 8 + j] = make_float4(f0.x, f0.y, f1.x, f1.y);
            }
        }
    }
}

// ---------------- fallback (no workspace): direct fp32, point-major --------
__global__ __launch_bounds__(256) void hash_embed_direct(
    const float* __restrict__ x, const float* __restrict__ emb,
    float2* __restrict__ out, int npts)
{
    int t = blockIdx.x * 256 + threadIdx.x;
    int l = t & 15, b = t >> 4;
    if (b >= npts) return;
    size_t xb = (size_t)b * 3;
    float scale = c_scale[l], hiv = (float)c_res[l] - 1.0f;
    float rx = (x[xb] + 1.0f) * scale, ry = (x[xb+1] + 1.0f) * scale, rz = (x[xb+2] + 1.0f) * scale;
    float fx = fminf(fmaxf(floorf(rx), 0.0f), hiv);
    float fy = fminf(fmaxf(floorf(ry), 0.0f), hiv);
    float fz = fminf(fmaxf(floorf(rz), 0.0f), hiv);
    float wx = rx - fx, wy = ry - fy, wz = rz - fz;
    uint32_t ix = (uint32_t)fx, iy = (uint32_t)fy, iz = (uint32_t)fz;
    uint32_t a0 = ix, a1 = ix + 1u, b0 = iy * P1, b1 = b0 + P1, c0 = iz * P2, c1 = c0 + P2;
    const float2* tb = (const float2*)emb + (size_t)l * TABLE_SIZE;
    float2 v0 = tb[(a0^b0^c0)&HASH_MASK], v1 = tb[(a1^b0^c0)&HASH_MASK];
    float2 v2 = tb[(a0^b1^c0)&HASH_MASK], v3 = tb[(a1^b1^c0)&HASH_MASK];
    float2 v4 = tb[(a0^b0^c1)&HASH_MASK], v5 = tb[(a1^b0^c1)&HASH_MASK];
    float2 v6 = tb[(a0^b1^c1)&HASH_MASK], v7 = tb[(a1^b1^c1)&HASH_MASK];
    float ux = 1.0f - wx, uy = 1.0f - wy, uz = 1.0f - wz;
    float w0 = ux*uy*uz, w1 = wx*uy*uz, w2 = ux*wy*uz, w3 = wx*wy*uz;
    float w4 = ux*uy*wz, w5 = wx*uy*wz, w6 = ux*wy*wz, w7 = wx*wy*wz;
    float o0 = w0*v0.x+w1*v1.x+w2*v2.x+w3*v3.x+w4*v4.x+w5*v5.x+w6*v6.x+w7*v7.x;
    float o1 = w0*v0.y+w1*v1.y+w2*v2.y+w3*v3.y+w4*v4.y+w5*v5.y+w6*v6.y+w7*v7.y;
    out[(size_t)b * N_LEVELS + l] = make_float2(o0, o1);
}

extern "C" void kernel_launch(void* const* d_in, const int* in_sizes, int n_in,
                              void* d_out, int out_size, void* d_ws, size_t ws_size,
                              hipStream_t stream)
{
    const float*  x   = (const float*)d_in[0];
    const float2* emb = (const float2*)d_in[1];
    int npts = in_sizes[0] / 3;

    size_t tmp_bytes = (size_t)npts * N_LEVELS * 4;        // half2 per (pt,lvl)
    size_t ht_bytes  = (size_t)N_DENSE * TABLE_SIZE * 4;   // 8 fp16 hash tables
    size_t cg_bytes  = (size_t)CELL_TOTAL * 32;            // cell-major grids
    size_t dn_bytes  = (size_t)DENSE_TOTAL * 4;            // vertex-dense grids

    int ht_total = N_DENSE * TABLE_SIZE;                   // 4.19M entries

    if (ws_size >= tmp_bytes + ht_bytes + cg_bytes) {      // preferred tier
        uint32_t* tmp = (uint32_t*)d_ws;
        uint32_t* ht  = (uint32_t*)((char*)d_ws + tmp_bytes);
        uint4*    cg  = (uint4*)   ((char*)d_ws + tmp_bytes + ht_bytes);

        hipLaunchKernelGGL(conv_hash, dim3((ht_total + 255) / 256), dim3(256),
                           0, stream, emb, ht, ht_total);
        hipLaunchKernelGGL(conv_cell, dim3(2000, N_DENSE), dim3(256),
                           0, stream, emb, cg);
        hipLaunchKernelGGL(HIP_KERNEL_NAME(gather_lvl<true>),
                           dim3((npts + 511) / 512, N_LEVELS), dim3(256),
                           0, stream, x, ht, (const uint32_t*)nullptr, cg, tmp, npts);
        hipLaunchKernelGGL(transpose_k, dim3((npts + 511) / 512), dim3(256),
                           0, stream, tmp, (float4*)d_out, npts);
    } else if (ws_size >= tmp_bytes + ht_bytes + dn_bytes) {  // round-3 tier
        uint32_t* tmp = (uint32_t*)d_ws;
        uint32_t* ht  = (uint32_t*)((char*)d_ws + tmp_bytes);
        uint32_t* dn  = (uint32_t*)((char*)d_ws + tmp_bytes + ht_bytes);

        hipLaunchKernelGGL(conv_hash, dim3((ht_total + 255) / 256), dim3(256),
                           0, stream, emb, ht, ht_total);
        hipLaunchKernelGGL(conv_dense, dim3(2077, N_DENSE), dim3(256),
                           0, stream, emb, dn);
        hipLaunchKernelGGL(HIP_KERNEL_NAME(gather_lvl<false>),
                           dim3((npts + 511) / 512, N_LEVELS), dim3(256),
                           0, stream, x, ht, dn, (const uint4*)nullptr, tmp, npts);
        hipLaunchKernelGGL(transpose_k, dim3((npts + 511) / 512), dim3(256),
                           0, stream, tmp, (float4*)d_out, npts);
    } else {                                               // no workspace
        int total = npts * N_LEVELS;
        hipLaunchKernelGGL(hash_embed_direct, dim3((total + 255) / 256), dim3(256),
                           0, stream, (const float*)x, (const float*)emb,
                           (float2*)d_out, npts);
    }
}

// Round 3
// 459.006 us; speedup vs baseline: 1.0697x; 1.0023x over previous
//
#include <hip/hip_runtime.h>
#include <hip/hip_fp16.h>
#include <stdint.h>

// InstantNGP hash-grid embedding, round 6 (= round-5 resubmit; infra flake).
// Round-4 counters: gather 263us, FETCH +133MB (levels 6-7 cell grids 8.4/16.4MB
// thrash the 4MiB/XCD L2 -> L3-latency-bound), hash phases ~= 8 L2-req/pt
// (L1 does NOT merge the x-pair into one request). Attack:
//  (a) hash levels: dwordx4 window at h&~3 covers BOTH x-corners for 75% of
//      lanes (PRIME_x==1 -> h1 = h0 ^ (ix^(ix+1)), mask<=3 w.p. 0.75);
//      exec-masked scalar fallback for the rest. 8 -> ~5 L2 req/pt.
//  (b) levels 6-7: pair-major vertex grids (8B entry = both x-corners,
//      2x duplication, 2.2/4.2MB -> L2-resident) -> 4 aligned dwordx2/pt.
//  (c) levels 0-5 stay cell-major (<=4MB/level, L2-resident).

#define N_LEVELS   16
#define LOG2_T     19
#define TABLE_SIZE (1u << LOG2_T)
#define HASH_MASK  (TABLE_SIZE - 1u)
#define P1 2654435761u
#define P2 805459861u
#define N_CELL     6          // levels 0..5: cell-major
#define N_DENSE    8          // levels 0..7 are dense-staged overall

__constant__ int   c_res[N_LEVELS]   = {16, 20, 25, 32, 40, 50, 64, 80,
                                        101, 128, 161, 203, 256, 322, 406, 512};
// scale = res/2 (exact fp32); rel=(x+1)*scale matches ref to <=1 ulp.
__constant__ float c_scale[N_LEVELS] = {8.0f, 10.0f, 12.5f, 16.0f, 20.0f, 25.0f,
                                        32.0f, 40.0f, 50.5f, 64.0f, 80.5f, 101.5f,
                                        128.0f, 161.0f, 203.0f, 256.0f};

// ---- cell-major (levels 0..5): R^3 cells, 32B (8 half2) each --------------
__constant__ uint32_t c_coff[N_CELL] = {0, 4096, 12096, 27721, 60489, 124489};
#define CELL_TOTAL 249489u    // cells, *32B = 7.98MB

// ---- pair-major (levels 6..7): [S][S][R] entries, 8B = (v(ix),v(ix+1)) ----
__constant__ uint32_t c_poff[2] = {0, 270400};   // level6: 65*65*64
#define PAIR_TOTAL 795280u    // + level7: 81*81*80; *8B = 6.36MB

// ---- vertex-dense fallback tier (round-3 layout) --------------------------
__constant__ uint32_t c_dim[N_DENSE]  = {17, 21, 26, 33, 41, 51, 65, 81};
__constant__ uint32_t c_doff[N_DENSE] = {0, 4913, 14174, 31750,
                                         67687, 136608, 269259, 543884};
#define DENSE_TOTAL 1075325u

// ---------------- pass 0a: fp16-convert hash tables (levels 8..15) ---------
__global__ __launch_bounds__(256) void conv_hash(
    const float2* __restrict__ emb, uint32_t* __restrict__ ht, int total)
{
    int i = blockIdx.x * 256 + threadIdx.x;
    if (i >= total) return;
    float2 v = emb[(size_t)N_DENSE * TABLE_SIZE + i];   // levels 8..15 contiguous
    __half2 h = __float22half2_rn(v);
    ht[i] = *(uint32_t*)&h;
}

// ---------------- pass 0b: cell-major fp16 grids (levels 0..5) -------------
__global__ __launch_bounds__(256) void conv_cell(
    const float2* __restrict__ emb, uint4* __restrict__ cg)
{
    int l = blockIdx.y;
    uint32_t c = blockIdx.x * 256 + threadIdx.x;
    uint32_t R = (uint32_t)c_res[l];
    if (c >= R * R * R) return;
    uint32_t ix = c % R;
    uint32_t r  = c / R;
    uint32_t iy = r % R;
    uint32_t iz = r / R;

    const float2* __restrict__ tb = emb + (size_t)l * TABLE_SIZE;
    uint32_t a0 = ix,      a1 = ix + 1u;     // prime[0]==1
    uint32_t b0 = iy * P1, b1 = b0 + P1;
    uint32_t d0 = iz * P2, d1 = d0 + P2;

    float2 f0 = tb[(a0 ^ b0 ^ d0) & HASH_MASK];
    float2 f1 = tb[(a1 ^ b0 ^ d0) & HASH_MASK];
    float2 f2 = tb[(a0 ^ b1 ^ d0) & HASH_MASK];
    float2 f3 = tb[(a1 ^ b1 ^ d0) & HASH_MASK];
    float2 f4 = tb[(a0 ^ b0 ^ d1) & HASH_MASK];
    float2 f5 = tb[(a1 ^ b0 ^ d1) & HASH_MASK];
    float2 f6 = tb[(a0 ^ b1 ^ d1) & HASH_MASK];
    float2 f7 = tb[(a1 ^ b1 ^ d1) & HASH_MASK];

    __half2 h0 = __float22half2_rn(f0), h1 = __float22half2_rn(f1);
    __half2 h2 = __float22half2_rn(f2), h3 = __float22half2_rn(f3);
    __half2 h4 = __float22half2_rn(f4), h5 = __float22half2_rn(f5);
    __half2 h6 = __float22half2_rn(f6), h7 = __float22half2_rn(f7);

    uint32_t base = 2u * (c_coff[l] + c);
    cg[base]      = make_uint4(*(uint32_t*)&h0, *(uint32_t*)&h1,
                               *(uint32_t*)&h2, *(uint32_t*)&h3);
    cg[base + 1u] = make_uint4(*(uint32_t*)&h4, *(uint32_t*)&h5,
                               *(uint32_t*)&h6, *(uint32_t*)&h7);
}

// ---------------- pass 0c: pair-major fp16 grids (levels 6..7) -------------
__global__ __launch_bounds__(256) void conv_pair(
    const float2* __restrict__ emb, uint2* __restrict__ pp)
{
    int li = blockIdx.y;                       // 0 -> level 6, 1 -> level 7
    int l  = 6 + li;
    uint32_t e = blockIdx.x * 256 + threadIdx.x;
    uint32_t R = (uint32_t)c_res[l];
    uint32_t S = R + 1u;
    if (e >= R * S * S) return;
    uint32_t ix = e % R;
    uint32_t r  = e / R;
    uint32_t iy = r % S;
    uint32_t iz = r / S;
    const float2* __restrict__ tb = emb + (size_t)l * TABLE_SIZE;
    uint32_t hy = iy * P1, hz = iz * P2;
    uint32_t h0 = (ix        ^ hy ^ hz) & HASH_MASK;
    uint32_t h1 = ((ix + 1u) ^ hy ^ hz) & HASH_MASK;
    __half2 a = __float22half2_rn(tb[h0]);
    __half2 b = __float22half2_rn(tb[h1]);
    pp[c_poff[li] + e] = make_uint2(*(uint32_t*)&a, *(uint32_t*)&b);
}

// ---------------- pass 0b (fallback tier): vertex-dense fp16 grids ---------
__global__ __launch_bounds__(256) void conv_dense(
    const float2* __restrict__ emb, uint32_t* __restrict__ dn)
{
    int l = blockIdx.y;
    uint32_t v = blockIdx.x * 256 + threadIdx.x;
    uint32_t S = c_dim[l];
    if (v >= S * S * S) return;
    uint32_t ix = v % S;
    uint32_t r  = v / S;
    uint32_t iy = r % S;
    uint32_t iz = r / S;
    uint32_t h  = (ix ^ (iy * P1) ^ (iz * P2)) & HASH_MASK;
    float2 val  = emb[(size_t)l * TABLE_SIZE + h];
    __half2 hv  = __float22half2_rn(val);
    dn[c_doff[l] + v] = *(uint32_t*)&hv;
}

// select element idx (0..3) of a uint4 without scratch (cndmask chain)
__device__ __forceinline__ uint32_t sel4(uint4 e, uint32_t idx)
{
    uint32_t lo = (idx & 1u) ? e.y : e.x;
    uint32_t hi = (idx & 1u) ? e.w : e.z;
    return (idx & 2u) ? hi : lo;
}

// ---------------- gather core ----------------------------------------------
// NEWPATH=1: cell(0..5)/pair(6..7)/hash-x4-window(8..15)
// NEWPATH=0: round-3 vertex-dense(0..7)/plain-hash(8..15)
template <bool NEWPATH>
__device__ __forceinline__ void do_point(
    int l, int b, int npts,
    const float* __restrict__ x,
    const uint32_t* __restrict__ ht,
    const uint4*    __restrict__ cg,
    const uint2*    __restrict__ pp,
    const uint32_t* __restrict__ dn,
    uint32_t* __restrict__ tmp)
{
    if (b >= npts) return;
    size_t xb = (size_t)b * 3;
    float xx = x[xb], xy = x[xb + 1], xz = x[xb + 2];

    float scale = c_scale[l];
    float hiv   = (float)c_res[l] - 1.0f;

    float rx = (xx + 1.0f) * scale;
    float ry = (xy + 1.0f) * scale;
    float rz = (xz + 1.0f) * scale;

    float fx = fminf(fmaxf(floorf(rx), 0.0f), hiv);
    float fy = fminf(fmaxf(floorf(ry), 0.0f), hiv);
    float fz = fminf(fmaxf(floorf(rz), 0.0f), hiv);

    float wx = rx - fx, wy = ry - fy, wz = rz - fz;
    uint32_t ix = (uint32_t)fx, iy = (uint32_t)fy, iz = (uint32_t)fz;

    uint32_t u0, u1, u2, u3, u4, u5, u6, u7;
    if (NEWPATH && l < N_CELL) {              // cell-major: 1 line/pt
        uint32_t R    = (uint32_t)c_res[l];
        uint32_t cidx = (iz * R + iy) * R + ix;
        uint32_t base = 2u * (c_coff[l] + cidx);
        uint4 lo = cg[base];
        uint4 hi = cg[base + 1u];
        u0 = lo.x; u1 = lo.y; u2 = lo.z; u3 = lo.w;
        u4 = hi.x; u5 = hi.y; u6 = hi.z; u7 = hi.w;
    } else if (NEWPATH && l < N_DENSE) {      // pair-major: 4 aligned dwordx2
        uint32_t R    = (uint32_t)c_res[l];
        uint32_t S    = R + 1u;
        uint32_t base = c_poff[l - N_CELL] + (iz * S + iy) * R + ix;
        uint32_t RS   = R * S;
        uint2 p0 = pp[base];
        uint2 p1 = pp[base + R];
        uint2 p2 = pp[base + RS];
        uint2 p3 = pp[base + RS + R];
        u0 = p0.x; u1 = p0.y; u2 = p1.x; u3 = p1.y;
        u4 = p2.x; u5 = p2.y; u6 = p3.x; u7 = p3.y;
    } else if (!NEWPATH && l < N_DENSE) {     // vertex-dense: 8 dwords
        uint32_t S    = c_dim[l];
        uint32_t base = c_doff[l] + (iz * S + iy) * S + ix;
        uint32_t S2   = S * S;
        u0 = dn[base];           u1 = dn[base + 1];
        u2 = dn[base + S];       u3 = dn[base + S + 1];
        u4 = dn[base + S2];      u5 = dn[base + S2 + 1];
        u6 = dn[base + S2 + S];  u7 = dn[base + S2 + S + 1];
    } else if (NEWPATH) {                     // hash, x4-window x-pairs
        const uint32_t* __restrict__ tb = ht + (size_t)(l - N_DENSE) * TABLE_SIZE;
        uint32_t mx = ix ^ (ix + 1u);         // h(ix+1) = h(ix) ^ mx (prime_x==1)
        uint32_t hy0 = iy * P1, hy1 = hy0 + P1;
        uint32_t hz0 = iz * P2, hz1 = hz0 + P2;
        uint32_t hA = (ix ^ hy0 ^ hz0) & HASH_MASK;
        uint32_t hB = (ix ^ hy1 ^ hz0) & HASH_MASK;
        uint32_t hC = (ix ^ hy0 ^ hz1) & HASH_MASK;
        uint32_t hD = (ix ^ hy1 ^ hz1) & HASH_MASK;
        bool win = (mx <= 3u);                // window covers both corners?

        uint4 eA = *(const uint4*)(tb + (hA & ~3u));
        uint4 eB = *(const uint4*)(tb + (hB & ~3u));
        uint4 eC = *(const uint4*)(tb + (hC & ~3u));
        uint4 eD = *(const uint4*)(tb + (hD & ~3u));

        u0 = sel4(eA, hA & 3u);
        u2 = sel4(eB, hB & 3u);
        u4 = sel4(eC, hC & 3u);
        u6 = sel4(eD, hD & 3u);

        if (win) {                            // 75% of lanes: free second corner
            u1 = sel4(eA, (hA ^ mx) & 3u);
            u3 = sel4(eB, (hB ^ mx) & 3u);
            u5 = sel4(eC, (hC ^ mx) & 3u);
            u7 = sel4(eD, (hD ^ mx) & 3u);
        } else {                              // exec-masked fallback loads
            u1 = tb[hA ^ mx];
            u3 = tb[hB ^ mx];
            u5 = tb[hC ^ mx];
            u7 = tb[hD ^ mx];
        }
    } else {                                  // plain hash (fallback tier)
        const uint32_t* __restrict__ tb = ht + (size_t)(l - N_DENSE) * TABLE_SIZE;
        uint32_t a0 = ix,      a1 = ix + 1u;
        uint32_t b0 = iy * P1, b1 = b0 + P1;
        uint32_t c0 = iz * P2, c1 = c0 + P2;
        u0 = tb[(a0 ^ b0 ^ c0) & HASH_MASK];
        u1 = tb[(a1 ^ b0 ^ c0) & HASH_MASK];
        u2 = tb[(a0 ^ b1 ^ c0) & HASH_MASK];
        u3 = tb[(a1 ^ b1 ^ c0) & HASH_MASK];
        u4 = tb[(a0 ^ b0 ^ c1) & HASH_MASK];
        u5 = tb[(a1 ^ b0 ^ c1) & HASH_MASK];
        u6 = tb[(a0 ^ b1 ^ c1) & HASH_MASK];
        u7 = tb[(a1 ^ b1 ^ c1) & HASH_MASK];
    }

    float2 v0 = __half22float2(*(__half2*)&u0);
    float2 v1 = __half22float2(*(__half2*)&u1);
    float2 v2 = __half22float2(*(__half2*)&u2);
    float2 v3 = __half22float2(*(__half2*)&u3);
    float2 v4 = __half22float2(*(__half2*)&u4);
    float2 v5 = __half22float2(*(__half2*)&u5);
    float2 v6 = __half22float2(*(__half2*)&u6);
    float2 v7 = __half22float2(*(__half2*)&u7);

    float ux = 1.0f - wx, uy = 1.0f - wy, uz = 1.0f - wz;
    float w0 = ux * uy * uz, w1 = wx * uy * uz;
    float w2 = ux * wy * uz, w3 = wx * wy * uz;
    float w4 = ux * uy * wz, w5 = wx * uy * wz;
    float w6 = ux * wy * wz, w7 = wx * wy * wz;

    float o0 = w0 * v0.x + w1 * v1.x + w2 * v2.x + w3 * v3.x
             + w4 * v4.x + w5 * v5.x + w6 * v6.x + w7 * v7.x;
    float o1 = w0 * v0.y + w1 * v1.y + w2 * v2.y + w3 * v3.y
             + w4 * v4.y + w5 * v5.y + w6 * v6.y + w7 * v7.y;

    __half2 r = __float22half2_rn(make_float2(o0, o1));
    tmp[(size_t)l * npts + b] = *(uint32_t*)&r;
}

// grid.y = level (dispatch x-fastest -> level phases); 2 points/thread.
template <bool NEWPATH>
__global__ __launch_bounds__(256) void gather_lvl(
    const float* __restrict__ x,
    const uint32_t* __restrict__ ht,
    const uint4*    __restrict__ cg,
    const uint2*    __restrict__ pp,
    const uint32_t* __restrict__ dn,
    uint32_t* __restrict__ tmp, int npts)
{
    const int l  = blockIdx.y;
    const int bA = blockIdx.x * 512 + threadIdx.x;
    do_point<NEWPATH>(l, bA,       npts, x, ht, cg, pp, dn, tmp);
    do_point<NEWPATH>(l, bA + 256, npts, x, ht, cg, pp, dn, tmp);
}

// ---------------- pass 2: tmp[l][b] (half2) -> out[b][l] (float2) ----------
__global__ __launch_bounds__(256) void transpose_k(
    const uint32_t* __restrict__ tmp, float4* __restrict__ out4, int npts)
{
    __shared__ uint32_t sm[N_LEVELS][514];    // pad 2 -> <=2-way bank conflicts

    const int b0 = blockIdx.x * 512;
    const int t  = threadIdx.x;

    if (b0 + 512 <= npts) {
        #pragma unroll
        for (int l = 0; l < N_LEVELS; ++l) {
            uint2 u = *(const uint2*)&tmp[(size_t)l * npts + b0 + 2 * t];
            *(uint2*)&sm[l][2 * t] = u;       // single ds_write_b64
        }
        __syncthreads();
        #pragma unroll
        for (int k = 0; k < 16; ++k) {
            int q = k * 256 + t;              // float4 index in tile (0..4095)
            int p = q >> 3;                   // point in tile
            int j = q & 7;                    // float4 within point
            uint32_t a = sm[2 * j][p], b = sm[2 * j + 1][p];
            float2 f0 = __half22float2(*(__half2*)&a);
            float2 f1 = __half22float2(*(__half2*)&b);
            out4[(size_t)(b0 + p) * 8 + j] = make_float4(f0.x, f0.y, f1.x, f1.y);
        }
    } else {                                  // guarded tail tile
        for (int l = 0; l < N_LEVELS; ++l) {
            for (int s = 0; s < 2; ++s) {
                int b = b0 + 2 * t + s;
                if (b < npts) sm[l][2 * t + s] = tmp[(size_t)l * npts + b];
            }
        }
        __syncthreads();
        for (int k = 0; k < 16; ++k) {
            int q = k * 256 + t;
            int p = q >> 3, j = q & 7;
            if (b0 + p < npts) {
                uint32_t a = sm[2 * j][p], b = sm[2 * j + 1][p];
                float2 f0 = __half22float2(*(__half2*)&a);
                float2 f1 = __half22float2(*(__half2*)&b);
                out4[(size_t)(b0 + p) * 8 + j] = make_float4(f0.x, f0.y, f1.x, f1.y);
            }
        }
    }
}

// ---------------- fallback (no workspace): direct fp32, point-major --------
__global__ __launch_bounds__(256) void hash_embed_direct(
    const float* __restrict__ x, const float* __restrict__ emb,
    float2* __restrict__ out, int npts)
{
    int t = blockIdx.x * 256 + threadIdx.x;
    int l = t & 15, b = t >> 4;
    if (b >= npts) return;
    size_t xb = (size_t)b * 3;
    float scale = c_scale[l], hiv = (float)c_res[l] - 1.0f;
    float rx = (x[xb] + 1.0f) * scale, ry = (x[xb+1] + 1.0f) * scale, rz = (x[xb+2] + 1.0f) * scale;
    float fx = fminf(fmaxf(floorf(rx), 0.0f), hiv);
    float fy = fminf(fmaxf(floorf(ry), 0.0f), hiv);
    float fz = fminf(fmaxf(floorf(rz), 0.0f), hiv);
    float wx = rx - fx, wy = ry - fy, wz = rz - fz;
    uint32_t ix = (uint32_t)fx, iy = (uint32_t)fy, iz = (uint32_t)fz;
    uint32_t a0 = ix, a1 = ix + 1u, b0 = iy * P1, b1 = b0 + P1, c0 = iz * P2, c1 = c0 + P2;
    const float2* tb = (const float2*)emb + (size_t)l * TABLE_SIZE;
    float2 v0 = tb[(a0^b0^c0)&HASH_MASK], v1 = tb[(a1^b0^c0)&HASH_MASK];
    float2 v2 = tb[(a0^b1^c0)&HASH_MASK], v3 = tb[(a1^b1^c0)&HASH_MASK];
    float2 v4 = tb[(a0^b0^c1)&HASH_MASK], v5 = tb[(a1^b0^c1)&HASH_MASK];
    float2 v6 = tb[(a0^b1^c1)&HASH_MASK], v7 = tb[(a1^b1^c1)&HASH_MASK];
    float ux = 1.0f - wx, uy = 1.0f - wy, uz = 1.0f - wz;
    float w0 = ux*uy*uz, w1 = wx*uy*uz, w2 = ux*wy*uz, w3 = wx*wy*uz;
    float w4 = ux*uy*wz, w5 = wx*uy*wz, w6 = ux*wy*wz, w7 = wx*wy*wz;
    float o0 = w0*v0.x+w1*v1.x+w2*v2.x+w3*v3.x+w4*v4.x+w5*v5.x+w6*v6.x+w7*v7.x;
    float o1 = w0*v0.y+w1*v1.y+w2*v2.y+w3*v3.y+w4*v4.y+w5*v5.y+w6*v6.y+w7*v7.y;
    out[(size_t)b * N_LEVELS + l] = make_float2(o0, o1);
}

extern "C" void kernel_launch(void* const* d_in, const int* in_sizes, int n_in,
                              void* d_out, int out_size, void* d_ws, size_t ws_size,
                              hipStream_t stream)
{
    const float*  x   = (const float*)d_in[0];
    const float2* emb = (const float2*)d_in[1];
    int npts = in_sizes[0] / 3;

    size_t tmp_bytes = (size_t)npts * N_LEVELS * 4;        // half2 per (pt,lvl)
    size_t ht_bytes  = (size_t)N_DENSE * TABLE_SIZE * 4;   // 8 fp16 hash tables
    size_t cg_bytes  = (size_t)CELL_TOTAL * 32;            // cell grids 0..5
    size_t pp_bytes  = (size_t)PAIR_TOTAL * 8;             // pair grids 6..7
    size_t dn_bytes  = (size_t)DENSE_TOTAL * 4;            // vertex-dense (fb)

    int ht_total = N_DENSE * TABLE_SIZE;                   // 4.19M entries

    if (ws_size >= tmp_bytes + ht_bytes + cg_bytes + pp_bytes) {   // preferred
        uint32_t* tmp = (uint32_t*)d_ws;
        uint32_t* ht  = (uint32_t*)((char*)d_ws + tmp_bytes);
        uint4*    cg  = (uint4*)   ((char*)d_ws + tmp_bytes + ht_bytes);
        uint2*    pp  = (uint2*)   ((char*)d_ws + tmp_bytes + ht_bytes + cg_bytes);

        hipLaunchKernelGGL(conv_hash, dim3((ht_total + 255) / 256), dim3(256),
                           0, stream, emb, ht, ht_total);
        hipLaunchKernelGGL(conv_cell, dim3(489, N_CELL), dim3(256),
                           0, stream, emb, cg);
        hipLaunchKernelGGL(conv_pair, dim3(2051, 2), dim3(256),
                           0, stream, emb, pp);
        hipLaunchKernelGGL(HIP_KERNEL_NAME(gather_lvl<true>),
                           dim3((npts + 511) / 512, N_LEVELS), dim3(256),
                           0, stream, x, ht, cg, pp, (const uint32_t*)nullptr,
                           tmp, npts);
        hipLaunchKernelGGL(transpose_k, dim3((npts + 511) / 512), dim3(256),
                           0, stream, tmp, (float4*)d_out, npts);
    } else if (ws_size >= tmp_bytes + ht_bytes + dn_bytes) {       // round-3 tier
        uint32_t* tmp = (uint32_t*)d_ws;
        uint32_t* ht  = (uint32_t*)((char*)d_ws + tmp_bytes);
        uint32_t* dn  = (uint32_t*)((char*)d_ws + tmp_bytes + ht_bytes);

        hipLaunchKernelGGL(conv_hash, dim3((ht_total + 255) / 256), dim3(256),
                           0, stream, emb, ht, ht_total);
        hipLaunchKernelGGL(conv_dense, dim3(2077, N_DENSE), dim3(256),
                           0, stream, emb, dn);
        hipLaunchKernelGGL(HIP_KERNEL_NAME(gather_lvl<false>),
                           dim3((npts + 511) / 512, N_LEVELS), dim3(256),
                           0, stream, x, ht, (const uint4*)nullptr,
                           (const uint2*)nullptr, dn, tmp, npts);
        hipLaunchKernelGGL(transpose_k, dim3((npts + 511) / 512), dim3(256),
                           0, stream, tmp, (float4*)d_out, npts);
    } else {                                               // no workspace
        int total = npts * N_LEVELS;
        hipLaunchKernelGGL(hash_embed_direct, dim3((total + 255) / 256), dim3(256),
                           0, stream, (const float*)x, (const float*)emb,
                           (float2*)d_out, npts);
    }
}